// Round 1
// baseline (469.995 us; speedup 1.0000x reference)
//
#include <hip/hip_runtime.h>

// NCC loss: five 9x9x9 box sums (I, J, I^2, J^2, I*J), stride 1, pad 4,
// count_include_pad (divisor always 729), then ncc = cov^2/(varI*varJ+eps),
// output = -mean(ncc). Shapes fixed: [2,1,192,192,192] fp32.

#define S   192
#define NB  2
#define TX  16
#define TY  16
#define KZ  48
#define RAD 4
#define WIN 9
#define NSL (KZ + 2*RAD)   // 56 input slices per chunk
#define HX  (TX + 2*RAD)   // 24 staged width
#define HY  (TY + 2*RAD)   // 24 staged height
#define NVOX (2.0 * S * S * S)   // 14,155,776

__global__ void ncc_init(double* ws) { ws[0] = 0.0; }

__global__ void ncc_final(const double* __restrict__ ws, float* __restrict__ out) {
    out[0] = (float)(-ws[0] / NVOX);
}

__global__ __launch_bounds__(TX * TY) void ncc_main(const float* __restrict__ I,
                                                    const float* __restrict__ J,
                                                    double* __restrict__ ws) {
    // LDS: stage (2*2304B) + x-sums (7680B) + ring (46080B) + red (16B) = ~58 KB
    __shared__ float sI[HY][HX];
    __shared__ float sJ[HY][HX];
    __shared__ float xs[5][HY][TX];
    __shared__ float ring[WIN][5][TY][TX];
    __shared__ float red[4];

    const int tx  = threadIdx.x;            // 0..15
    const int ty  = threadIdx.y;            // 0..15
    const int tid = ty * TX + tx;           // 0..255

    const int x0 = blockIdx.x * TX;
    const int y0 = blockIdx.y * TY;
    const int zc = blockIdx.z & 3;          // 4 z-chunks
    const int b  = blockIdx.z >> 2;         // batch
    const int z0 = zc * KZ;

    const float* Ib = I + (size_t)b * S * S * S;
    const float* Jb = J + (size_t)b * S * S * S;

    // zero my own ring slots (only this thread ever touches them -> no barrier)
    #pragma unroll
    for (int p = 0; p < WIN; ++p)
        #pragma unroll
        for (int q = 0; q < 5; ++q)
            ring[p][q][ty][tx] = 0.f;

    float run0 = 0.f, run1 = 0.f, run2 = 0.f, run3 = 0.f, run4 = 0.f;
    float acc = 0.f;
    int phase = 0;

    for (int idx = 0; idx < NSL; ++idx) {
        const int zi = z0 - RAD + idx;
        const bool zv = ((unsigned)zi < (unsigned)S);   // block-uniform
        float n0, n1, n2, n3, n4;
        if (zv) {
            __syncthreads();   // protect sI/sJ/xs from previous slice's readers
            // ---- stage one z-slice with xy halo, zero-padded ----
            const float* Isl = Ib + (size_t)zi * S * S;
            const float* Jsl = Jb + (size_t)zi * S * S;
            for (int i = tid; i < HY * HX; i += TX * TY) {
                const int ly = i / HX;
                const int lx = i - ly * HX;
                const int gy = y0 - RAD + ly;
                const int gx = x0 - RAD + lx;
                float vi = 0.f, vj = 0.f;
                if (((unsigned)gy < (unsigned)S) & ((unsigned)gx < (unsigned)S)) {
                    const size_t o = (size_t)gy * S + gx;
                    vi = Isl[o];
                    vj = Jsl[o];
                }
                sI[ly][lx] = vi;
                sJ[ly][lx] = vj;
            }
            __syncthreads();
            // ---- x-direction 9-tap sums for 5 quantities ----
            for (int t = tid; t < HY * TX; t += TX * TY) {
                const int r = t >> 4;          // staged row 0..23
                const int c = t & (TX - 1);    // output x 0..15
                float a0 = 0.f, a1 = 0.f, a2 = 0.f, a3 = 0.f, a4 = 0.f;
                #pragma unroll
                for (int dx = 0; dx < WIN; ++dx) {
                    const float iv = sI[r][c + dx];
                    const float jv = sJ[r][c + dx];
                    a0 += iv;
                    a1 += jv;
                    a2 += iv * iv;
                    a3 += jv * jv;
                    a4 += iv * jv;
                }
                xs[0][r][c] = a0;
                xs[1][r][c] = a1;
                xs[2][r][c] = a2;
                xs[3][r][c] = a3;
                xs[4][r][c] = a4;
            }
            __syncthreads();
            // ---- y-direction 9-tap gather -> this slice's xy-sums ----
            n0 = n1 = n2 = n3 = n4 = 0.f;
            #pragma unroll
            for (int dy = 0; dy < WIN; ++dy) {
                n0 += xs[0][ty + dy][tx];
                n1 += xs[1][ty + dy][tx];
                n2 += xs[2][ty + dy][tx];
                n3 += xs[3][ty + dy][tx];
                n4 += xs[4][ty + dy][tx];
            }
        } else {
            n0 = n1 = n2 = n3 = n4 = 0.f;   // padded z-slice contributes zero
        }
        // ---- z running sum via 9-deep ring (own slots only) ----
        {
            const float o0 = ring[phase][0][ty][tx];
            const float o1 = ring[phase][1][ty][tx];
            const float o2 = ring[phase][2][ty][tx];
            const float o3 = ring[phase][3][ty][tx];
            const float o4 = ring[phase][4][ty][tx];
            run0 += n0 - o0;
            run1 += n1 - o1;
            run2 += n2 - o2;
            run3 += n3 - o3;
            run4 += n4 - o4;
            ring[phase][0][ty][tx] = n0;
            ring[phase][1][ty][tx] = n1;
            ring[phase][2][ty][tx] = n2;
            ring[phase][3][ty][tx] = n3;
            ring[phase][4][ty][tx] = n4;
        }
        if (++phase == WIN) phase = 0;
        // ---- emit NCC for out_z = z0 + idx - 8 once window complete ----
        if (idx >= 2 * RAD) {
            const float inv = 1.0f / 729.0f;
            const float mI  = run0 * inv;
            const float mJ  = run1 * inv;
            const float vI  = run2 * inv - mI * mI;
            const float vJ  = run3 * inv - mJ * mJ;
            const float cIJ = run4 * inv - mI * mJ;
            const float ncc = (cIJ * cIJ) / (vI * vJ + 1e-5f);
            acc += ncc;
        }
    }

    // ---- block reduction: wave shuffle (64) -> LDS -> one double atomic ----
    float v = acc;
    #pragma unroll
    for (int off = 32; off >= 1; off >>= 1)
        v += __shfl_down(v, off, 64);
    const int lane = tid & 63;
    const int wid  = tid >> 6;
    __syncthreads();   // ring/xs no longer needed; ensure all done before red reuse
    if (lane == 0) red[wid] = v;
    __syncthreads();
    if (tid == 0) {
        const float bs = red[0] + red[1] + red[2] + red[3];
        atomicAdd(ws, (double)bs);
    }
}

extern "C" void kernel_launch(void* const* d_in, const int* in_sizes, int n_in,
                              void* d_out, int out_size, void* d_ws, size_t ws_size,
                              hipStream_t stream) {
    const float* I = (const float*)d_in[0];   // y_pred
    const float* J = (const float*)d_in[1];   // y_true
    double* ws = (double*)d_ws;
    float* out = (float*)d_out;

    hipLaunchKernelGGL(ncc_init, dim3(1), dim3(1), 0, stream, ws);

    dim3 grid(S / TX, S / TY, (S / KZ) * NB);   // 12 x 12 x 8 = 1152 blocks
    dim3 blk(TX, TY);                           // 256 threads
    hipLaunchKernelGGL(ncc_main, grid, blk, 0, stream, I, J, ws);

    hipLaunchKernelGGL(ncc_final, dim3(1), dim3(1), 0, stream, ws, out);
}

// Round 2
// 261.225 us; speedup vs baseline: 1.7992x; 1.7992x over previous
//
#include <hip/hip_runtime.h>

// NCC loss: five 9x9x9 box sums (I, J, I^2, J^2, I*J), stride 1, pad 4,
// count_include_pad (divisor 729), ncc = cov^2/(varI*varJ+eps), out = -mean.
// Shapes fixed: [2,1,192,192,192] fp32.
//
// R2 structure: per block a 16x16 xy-tile over a 64-deep z-chunk.
// Separable 9-tap sums: x in LDS stage -> xs (float4+float), y gather,
// z via a 9-deep REGISTER ring (z-loop unrolled by 9 so phase is static).
// Double-buffered stage slices, 2 barriers/slice, loads for slice k+1
// issued before the x-phase of slice k.

#define S    192
#define SS   (S * S)
#define TX   16
#define TY   16
#define KZ   64
#define RAD  4
#define WIN  9
#define NSL  (KZ + 2 * RAD)      // 72 staged slices = 8 * 9
#define HX   (TX + 2 * RAD)      // 24
#define HY   (TY + 2 * RAD)      // 24
#define NVOX (2.0 * S * S * S)

__global__ void ncc_init(double* ws) { ws[0] = 0.0; }

__global__ void ncc_final(const double* __restrict__ ws, float* __restrict__ out) {
    out[0] = (float)(-ws[0] / NVOX);
}

__global__ __launch_bounds__(256, 4) void ncc_main(const float* __restrict__ I,
                                                   const float* __restrict__ J,
                                                   double* __restrict__ ws) {
    // LDS ~17.4 KB: stage 9216 + xs4 6528 + xs1 1632 + red 16
    __shared__ float  sI[2][HY][HX];
    __shared__ float  sJ[2][HY][HX];
    __shared__ float4 xs4[HY][TX + 1];   // (sumI, sumJ, sumI2, sumJ2), +1 col pad
    __shared__ float  xs1[HY][TX + 1];   // sumIJ
    __shared__ float  red[4];

    const int tx  = threadIdx.x;
    const int ty  = threadIdx.y;
    const int tid = ty * TX + tx;

    const int bz = blockIdx.z;
    const int b  = (bz >= 3) ? 1 : 0;
    const int zc = bz - 3 * b;
    const int x0 = blockIdx.x * TX;
    const int y0 = blockIdx.y * TY;
    const int z0 = zc * KZ;

    const float* Ib = I + (size_t)b * S * SS;
    const float* Jb = J + (size_t)b * S * SS;

    // Staging slots: flat halo elements tid, tid+256, (tid+512 if tid<64).
    // Precompute plane offsets; -1 marks xy-out-of-range (zero pad).
    auto slot_off = [&](int e) -> int {
        const int ly = e / HX;
        const int lx = e - ly * HX;
        const int gy = y0 - RAD + ly;
        const int gx = x0 - RAD + lx;
        return (((unsigned)gy < (unsigned)S) & ((unsigned)gx < (unsigned)S))
                   ? (gy * S + gx) : -1;
    };
    const int off0 = slot_off(tid);
    const int off1 = slot_off(tid + 256);
    const int off2 = (tid < 64) ? slot_off(tid + 512) : -1;

    // Register ring: 9 phases x 5 fields (static indices only -> VGPRs).
    float ring[WIN][5];
    #pragma unroll
    for (int p = 0; p < WIN; ++p)
        #pragma unroll
        for (int q = 0; q < 5; ++q)
            ring[p][q] = 0.f;

    float run0 = 0.f, run1 = 0.f, run2 = 0.f, run3 = 0.f, run4 = 0.f;
    float acc = 0.f;

    // Prologue: load slice idx=0 (zi = z0-4) into pipeline regs.
    float vi0 = 0.f, vj0 = 0.f, vi1 = 0.f, vj1 = 0.f, vi2 = 0.f, vj2 = 0.f;
    {
        const int zi = z0 - RAD;
        if ((unsigned)zi < (unsigned)S) {
            const float* Isl = Ib + (size_t)zi * SS;
            const float* Jsl = Jb + (size_t)zi * SS;
            if (off0 >= 0) { vi0 = Isl[off0]; vj0 = Jsl[off0]; }
            if (off1 >= 0) { vi1 = Isl[off1]; vj1 = Jsl[off1]; }
            if (tid < 64 && off2 >= 0) { vi2 = Isl[off2]; vj2 = Jsl[off2]; }
        }
    }

    #pragma unroll 1
    for (int o = 0; o < NSL / WIN; ++o) {
        #pragma unroll
        for (int p = 0; p < WIN; ++p) {
            const int idx = o * WIN + p;
            const int cur = idx & 1;
            float* dI = &sI[cur][0][0];
            float* dJ = &sJ[cur][0][0];

            // (a) commit staged regs of slice idx into stage[cur]
            dI[tid]       = vi0;  dJ[tid]       = vj0;
            dI[tid + 256] = vi1;  dJ[tid + 256] = vj1;
            if (tid < 64) { dI[tid + 512] = vi2; dJ[tid + 512] = vj2; }
            __syncthreads();                                   // (b)

            // (d) issue global loads for slice idx+1 (fly during x-phase)
            {
                const int zn = z0 - RAD + idx + 1;
                vi0 = vj0 = vi1 = vj1 = vi2 = vj2 = 0.f;
                if ((unsigned)zn < (unsigned)S) {
                    const float* Isl = Ib + (size_t)zn * SS;
                    const float* Jsl = Jb + (size_t)zn * SS;
                    if (off0 >= 0) { vi0 = Isl[off0]; vj0 = Jsl[off0]; }
                    if (off1 >= 0) { vi1 = Isl[off1]; vj1 = Jsl[off1]; }
                    if (tid < 64 && off2 >= 0) { vi2 = Isl[off2]; vj2 = Jsl[off2]; }
                }
            }

            // (c) x-direction 9-tap sums: 384 rows-of-16 items over 256 threads
            {
                auto xrow = [&](int t) {
                    const int r = t >> 4;
                    const int c = t & (TX - 1);
                    const float* pi = &sI[cur][0][0] + r * HX + c;
                    const float* pj = &sJ[cur][0][0] + r * HX + c;
                    float a0 = 0.f, a1 = 0.f, a2 = 0.f, a3 = 0.f, a4 = 0.f;
                    #pragma unroll
                    for (int dx = 0; dx < WIN; ++dx) {
                        const float iv = pi[dx];
                        const float jv = pj[dx];
                        a0 += iv;
                        a1 += jv;
                        a2 += iv * iv;
                        a3 += jv * jv;
                        a4 += iv * jv;
                    }
                    xs4[r][c] = make_float4(a0, a1, a2, a3);
                    xs1[r][c] = a4;
                };
                xrow(tid);
                if (tid < 128) xrow(tid + 256);
            }
            __syncthreads();                                   // (e)

            // (f) y-direction 9-tap gather -> slice xy-sums
            float4 s4 = make_float4(0.f, 0.f, 0.f, 0.f);
            float  s1 = 0.f;
            #pragma unroll
            for (int dy = 0; dy < WIN; ++dy) {
                const float4 v = xs4[ty + dy][tx];
                s4.x += v.x; s4.y += v.y; s4.z += v.z; s4.w += v.w;
                s1 += xs1[ty + dy][tx];
            }

            // z running sum via register ring (phase p is compile-time)
            run0 += s4.x - ring[p][0];  ring[p][0] = s4.x;
            run1 += s4.y - ring[p][1];  ring[p][1] = s4.y;
            run2 += s4.z - ring[p][2];  ring[p][2] = s4.z;
            run3 += s4.w - ring[p][3];  ring[p][3] = s4.w;
            run4 += s1   - ring[p][4];  ring[p][4] = s1;

            // emit output z = z0 + idx - 8 once window is full
            if (idx >= 2 * RAD) {
                const float inv = 1.0f / 729.0f;
                const float mI  = run0 * inv;
                const float mJ  = run1 * inv;
                const float vI  = run2 * inv - mI * mI;
                const float vJ  = run3 * inv - mJ * mJ;
                const float cIJ = run4 * inv - mI * mJ;
                acc += (cIJ * cIJ) / (vI * vJ + 1e-5f);
            }
        }
    }

    // Block reduction: wave shuffle -> LDS -> one double atomic
    float v = acc;
    #pragma unroll
    for (int off = 32; off >= 1; off >>= 1)
        v += __shfl_down(v, off, 64);
    const int lane = tid & 63;
    const int wid  = tid >> 6;
    __syncthreads();
    if (lane == 0) red[wid] = v;
    __syncthreads();
    if (tid == 0) {
        atomicAdd(ws, (double)(red[0] + red[1] + red[2] + red[3]));
    }
}

extern "C" void kernel_launch(void* const* d_in, const int* in_sizes, int n_in,
                              void* d_out, int out_size, void* d_ws, size_t ws_size,
                              hipStream_t stream) {
    const float* I = (const float*)d_in[0];   // y_pred
    const float* J = (const float*)d_in[1];   // y_true
    double* ws = (double*)d_ws;
    float* out = (float*)d_out;

    hipLaunchKernelGGL(ncc_init, dim3(1), dim3(1), 0, stream, ws);

    dim3 grid(S / TX, S / TY, 3 * 2);   // 12 x 12 x 6 = 864 blocks
    dim3 blk(TX, TY);                   // 256 threads
    hipLaunchKernelGGL(ncc_main, grid, blk, 0, stream, I, J, ws);

    hipLaunchKernelGGL(ncc_final, dim3(1), dim3(1), 0, stream, ws, out);
}

// Round 3
// 258.090 us; speedup vs baseline: 1.8210x; 1.0121x over previous
//
#include <hip/hip_runtime.h>

// NCC loss: five 9x9x9 box sums (I, J, I^2, J^2, I*J), stride 1, pad 4,
// count_include_pad (divisor 729), ncc = cov^2/(varI*varJ+eps), out = -mean.
// Shapes fixed: [2,1,192,192,192] fp32.
//
// R3: 16x16 xy-tile, KZ=32 z-chunk (1728 blocks = 6.75/CU). Separable 9-tap:
// x-sums in LDS, y gather, z via a phase-free SHIFT REGISTER d[0..8] per field
// (static indices in small unrolled loops -> guaranteed VGPRs, no scratch;
// R2's phase-indexed ring was demoted to scratch: WRITE_SIZE 61.7MB, VGPR 64).
// Double-buffered stage, 2 barriers/slice, next-slice loads issued pre-x-phase.

#define S    192
#define SS   (S * S)
#define TX   16
#define TY   16
#define KZ   32
#define RAD  4
#define WIN  9
#define NSL  (KZ + 2 * RAD)      // 40 staged slices
#define HX   (TX + 2 * RAD)      // 24
#define HY   (TY + 2 * RAD)      // 24
#define NVOX (2.0 * S * S * S)

__global__ void ncc_init(double* ws) { ws[0] = 0.0; }

__global__ void ncc_final(const double* __restrict__ ws, float* __restrict__ out) {
    out[0] = (float)(-ws[0] / NVOX);
}

__global__ __launch_bounds__(256, 4) void ncc_main(const float* __restrict__ I,
                                                   const float* __restrict__ J,
                                                   double* __restrict__ ws) {
    // LDS ~17.4 KB: stage 9216 + xs4 6528 + xs1 1632 + red 16
    __shared__ float  sI[2][HY][HX];
    __shared__ float  sJ[2][HY][HX];
    __shared__ float4 xs4[HY][TX + 1];   // (sumI, sumJ, sumI2, sumJ2)
    __shared__ float  xs1[HY][TX + 1];   // sumIJ
    __shared__ float  red[4];

    const int tx  = threadIdx.x;
    const int ty  = threadIdx.y;
    const int tid = ty * TX + tx;

    const int bz = blockIdx.z;                // 0..11
    const int b  = (bz >= 6) ? 1 : 0;
    const int zc = bz - 6 * b;
    const int x0 = blockIdx.x * TX;
    const int y0 = blockIdx.y * TY;
    const int z0 = zc * KZ;

    const float* Ib = I + (size_t)b * S * SS;
    const float* Jb = J + (size_t)b * S * SS;

    // Staging slots: flat halo elements tid, tid+256, (tid+512 if tid<64).
    auto slot_off = [&](int e) -> int {
        const int ly = e / HX;
        const int lx = e - ly * HX;
        const int gy = y0 - RAD + ly;
        const int gx = x0 - RAD + lx;
        return (((unsigned)gy < (unsigned)S) & ((unsigned)gx < (unsigned)S))
                   ? (gy * S + gx) : -1;
    };
    const int off0 = slot_off(tid);
    const int off1 = slot_off(tid + 256);
    const int off2 = (tid < 64) ? slot_off(tid + 512) : -1;

    // Phase-free z shift registers: d_[f][k] = xy-sum of slice idx-9+k, field f.
    // Every access uses a compile-time index (small unrolled loops only).
    float d_[5][WIN];
    #pragma unroll
    for (int f = 0; f < 5; ++f)
        #pragma unroll
        for (int k = 0; k < WIN; ++k)
            d_[f][k] = 0.f;

    float run0 = 0.f, run1 = 0.f, run2 = 0.f, run3 = 0.f, run4 = 0.f;
    float acc = 0.f;

    // Prologue: load slice idx=0 (zi = z0-4) into pipeline regs.
    float vi0 = 0.f, vj0 = 0.f, vi1 = 0.f, vj1 = 0.f, vi2 = 0.f, vj2 = 0.f;
    {
        const int zi = z0 - RAD;
        if ((unsigned)zi < (unsigned)S) {
            const float* Isl = Ib + (size_t)zi * SS;
            const float* Jsl = Jb + (size_t)zi * SS;
            if (off0 >= 0) { vi0 = Isl[off0]; vj0 = Jsl[off0]; }
            if (off1 >= 0) { vi1 = Isl[off1]; vj1 = Jsl[off1]; }
            if (tid < 64 && off2 >= 0) { vi2 = Isl[off2]; vj2 = Jsl[off2]; }
        }
    }

    #pragma unroll 1
    for (int idx = 0; idx < NSL; ++idx) {
        const int cur = idx & 1;
        float* dI = &sI[cur][0][0];
        float* dJ = &sJ[cur][0][0];

        // (a) commit staged regs of slice idx into stage[cur]
        dI[tid]       = vi0;  dJ[tid]       = vj0;
        dI[tid + 256] = vi1;  dJ[tid + 256] = vj1;
        if (tid < 64) { dI[tid + 512] = vi2; dJ[tid + 512] = vj2; }
        __syncthreads();                                   // (b)

        // (c) issue global loads for slice idx+1 (fly during x-phase)
        {
            const int zn = z0 - RAD + idx + 1;
            vi0 = vj0 = vi1 = vj1 = vi2 = vj2 = 0.f;
            if ((unsigned)zn < (unsigned)S) {
                const float* Isl = Ib + (size_t)zn * SS;
                const float* Jsl = Jb + (size_t)zn * SS;
                if (off0 >= 0) { vi0 = Isl[off0]; vj0 = Jsl[off0]; }
                if (off1 >= 0) { vi1 = Isl[off1]; vj1 = Jsl[off1]; }
                if (tid < 64 && off2 >= 0) { vi2 = Isl[off2]; vj2 = Jsl[off2]; }
            }
        }

        // (d) x-direction 9-tap sums: 384 rows-of-16 items over 256 threads
        {
            auto xrow = [&](int t) {
                const int r = t >> 4;
                const int c = t & (TX - 1);
                const float* pi = dI + r * HX + c;
                const float* pj = dJ + r * HX + c;
                float a0 = 0.f, a1 = 0.f, a2 = 0.f, a3 = 0.f, a4 = 0.f;
                #pragma unroll
                for (int dx = 0; dx < WIN; ++dx) {
                    const float iv = pi[dx];
                    const float jv = pj[dx];
                    a0 += iv;
                    a1 += jv;
                    a2 += iv * iv;
                    a3 += jv * jv;
                    a4 += iv * jv;
                }
                xs4[r][c] = make_float4(a0, a1, a2, a3);
                xs1[r][c] = a4;
            };
            xrow(tid);
            if (tid < 128) xrow(tid + 256);
        }
        __syncthreads();                                   // (e)

        // (f) y-direction 9-tap gather -> this slice's xy-sums
        float4 s4 = make_float4(0.f, 0.f, 0.f, 0.f);
        float  s1 = 0.f;
        #pragma unroll
        for (int dy = 0; dy < WIN; ++dy) {
            const float4 v = xs4[ty + dy][tx];
            s4.x += v.x; s4.y += v.y; s4.z += v.z; s4.w += v.w;
            s1 += xs1[ty + dy][tx];
        }

        // (g) z running sums via shift register (all indices static)
        run0 += s4.x - d_[0][0];
        run1 += s4.y - d_[1][0];
        run2 += s4.z - d_[2][0];
        run3 += s4.w - d_[3][0];
        run4 += s1   - d_[4][0];
        #pragma unroll
        for (int k = 0; k < WIN - 1; ++k) {
            d_[0][k] = d_[0][k + 1];
            d_[1][k] = d_[1][k + 1];
            d_[2][k] = d_[2][k + 1];
            d_[3][k] = d_[3][k + 1];
            d_[4][k] = d_[4][k + 1];
        }
        d_[0][WIN - 1] = s4.x;
        d_[1][WIN - 1] = s4.y;
        d_[2][WIN - 1] = s4.z;
        d_[3][WIN - 1] = s4.w;
        d_[4][WIN - 1] = s1;

        // (h) emit output z = z0 + idx - 8 once window is full
        if (idx >= 2 * RAD) {
            const float inv = 1.0f / 729.0f;
            const float mI  = run0 * inv;
            const float mJ  = run1 * inv;
            const float vI  = run2 * inv - mI * mI;
            const float vJ  = run3 * inv - mJ * mJ;
            const float cIJ = run4 * inv - mI * mJ;
            acc += (cIJ * cIJ) / (vI * vJ + 1e-5f);
        }
    }

    // Block reduction: wave shuffle -> LDS -> one double atomic
    float v = acc;
    #pragma unroll
    for (int off = 32; off >= 1; off >>= 1)
        v += __shfl_down(v, off, 64);
    const int lane = tid & 63;
    const int wid  = tid >> 6;
    __syncthreads();
    if (lane == 0) red[wid] = v;
    __syncthreads();
    if (tid == 0) {
        atomicAdd(ws, (double)(red[0] + red[1] + red[2] + red[3]));
    }
}

extern "C" void kernel_launch(void* const* d_in, const int* in_sizes, int n_in,
                              void* d_out, int out_size, void* d_ws, size_t ws_size,
                              hipStream_t stream) {
    const float* I = (const float*)d_in[0];   // y_pred
    const float* J = (const float*)d_in[1];   // y_true
    double* ws = (double*)d_ws;
    float* out = (float*)d_out;

    hipLaunchKernelGGL(ncc_init, dim3(1), dim3(1), 0, stream, ws);

    dim3 grid(S / TX, S / TY, 6 * 2);   // 12 x 12 x 12 = 1728 blocks
    dim3 blk(TX, TY);                   // 256 threads
    hipLaunchKernelGGL(ncc_main, grid, blk, 0, stream, I, J, ws);

    hipLaunchKernelGGL(ncc_final, dim3(1), dim3(1), 0, stream, ws, out);
}